// Round 8
// baseline (330.864 us; speedup 1.0000x reference)
//
#include <hip/hip_runtime.h>
#include <hip/hip_bf16.h>

typedef unsigned short u16;
typedef __attribute__((ext_vector_type(8))) short bfrag;   // 8 x bf16 (4 VGPRs)
typedef __attribute__((ext_vector_type(4))) float ffrag;   // 4 x f32

// ---- problem constants ----
#define NWIN_TOT 1024      // B_ = 16 * 64 windows
#define NTOK 64            // tokens per window
#define CDIM 512
#define NHEAD 16
#define HDIM 32
#define NW 64              // mask windows

__device__ __forceinline__ u16 f2bf(float f) {
  union { float f; unsigned u; } v; v.f = f;
  unsigned r = v.u + 0x7fffu + ((v.u >> 16) & 1u);
  return (u16)(r >> 16);
}

__device__ __forceinline__ float bfhi2f(unsigned hi_bits) {  // bf16 in high 16 bits
  union { unsigned u; float f; } v; v.u = hi_bits; return v.f;
}

__device__ __forceinline__ ffrag mfma16(bfrag a, bfrag b, ffrag c) {
  return __builtin_amdgcn_mfma_f32_16x16x32_bf16(a, b, c, 0, 0, 0);
}

// async global->LDS, 16B per lane, linear LDS dest (wave base + lane*16)
__device__ __forceinline__ void gload16(const u16* src, u16* lds) {
  __builtin_amdgcn_global_load_lds(
      (const __attribute__((address_space(1))) unsigned int*)src,
      (__attribute__((address_space(3))) unsigned int*)lds, 16, 0, 0);
}

#define BAR() __builtin_amdgcn_s_barrier()
#define SCHED0() __builtin_amdgcn_sched_barrier(0)
#define VMW(n) do { asm volatile("s_waitcnt vmcnt(" #n ")" ::: "memory"); \
                    __builtin_amdgcn_sched_barrier(0); } while (0)

// ---------------------------------------------------------------------------
// prep: x -> bf16; weights -> bf16; combined bias+mask table (bf16, row-major)
// ---------------------------------------------------------------------------
__global__ __launch_bounds__(256) void k_prep(const float* __restrict__ x,
                                              const float* __restrict__ qkv_w,
                                              const float* __restrict__ proj_w,
                                              const int*   __restrict__ rel_index,
                                              const float* __restrict__ rpb,
                                              const float* __restrict__ mask,
                                              u16* __restrict__ xb,
                                              u16* __restrict__ wq, u16* __restrict__ wp,
                                              u16* __restrict__ combB) {
  int i = blockIdx.x * 256 + threadIdx.x;
  if (i < 4194304) {            // x -> bf16, 8 elems/thread
    int e = i * 8;
    const float4* xp = reinterpret_cast<const float4*>(x + e);
    float4 lo = xp[0], hi = xp[1];
    union { u16 u[8]; bfrag v; } pk;
    pk.u[0] = f2bf(lo.x); pk.u[1] = f2bf(lo.y); pk.u[2] = f2bf(lo.z); pk.u[3] = f2bf(lo.w);
    pk.u[4] = f2bf(hi.x); pk.u[5] = f2bf(hi.y); pk.u[6] = f2bf(hi.z); pk.u[7] = f2bf(hi.w);
    *reinterpret_cast<bfrag*>(xb + e) = pk.v;
    return;
  }
  i -= 4194304;
  if (i < 786432) { wq[i] = f2bf(qkv_w[i]); return; }
  i -= 786432;
  if (i < 262144) { wp[i] = f2bf(proj_w[i]); return; }
  i -= 262144;
  {                              // combB
    int wh = i >> 12, rc = i & 4095;
    int w0 = wh >> 4, h = wh & 15;
    combB[i] = f2bf(rpb[rel_index[rc] * 16 + h] + mask[(w0 << 12) + rc]);
  }
}

// ---------------------------------------------------------------------------
// 8-phase 256x256 GEMM, BK=64, 8 waves (2M x 4N), K=512 (8 K-tiles).
// K-loop + epilogue identical to R6 (verified 143 us, 0 bank conflicts).
// ---------------------------------------------------------------------------
#define MFMAQ(mh, nh, BARR) \
  _Pragma("unroll") for (int i_ = 0; i_ < 4; ++i_) \
  _Pragma("unroll") for (int n_ = 0; n_ < 2; ++n_) \
  _Pragma("unroll") for (int ks_ = 0; ks_ < 2; ++ks_) \
    acc[(mh)*4+i_][(nh)*2+n_] = mfma16(a_[i_*2+ks_], BARR[n_*2+ks_], acc[(mh)*4+i_][(nh)*2+n_]);

__global__ __launch_bounds__(512, 2) void k_gemm8(const u16* __restrict__ A,
                                                  const u16* __restrict__ W,
                                                  const float* __restrict__ bias,
                                                  u16* __restrict__ qws, u16* __restrict__ kws,
                                                  u16* __restrict__ vws) {
  constexpr int NT = 6;                            // N / 256
  constexpr int NWG = 256 * NT;                    // grid size (M/256 * NT)
  extern __shared__ __align__(16) u16 smem[];      // [2][2][256][64] = 128 KiB

  // XCD-bijective swizzle (NWG % 8 == 0), N-inner tile order
  const int bid = blockIdx.x;
  const int tile = (bid & 7) * (NWG >> 3) + (bid >> 3);
  const int bn = tile % NT, bm = tile / NT;
  const int brow = bm << 8, bcol = bn << 8;

  const int tid = threadIdx.x;
  const int wv = tid >> 6, lane = tid & 63, c15 = lane & 15, g = lane >> 4;
  const int wr = wv >> 2, wc = wv & 3;             // 2 x 4 wave grid
  const int rowA0 = wr * 128 + c15;                // + mh*64 + i*16
  const int rowB0 = wc * 64 + c15;                 // + nh*32 + n*16
  const ffrag zf = {0.f, 0.f, 0.f, 0.f};

  ffrag acc[8][4];
#pragma unroll
  for (int i = 0; i < 8; ++i)
#pragma unroll
    for (int n = 0; n < 4; ++n) acc[i][n] = zf;

  // stage one half-tile (128 rows x 64 cols) of matrix mat for K-tile t
  auto stage = [&](int t, int mat, int half) {
    u16* db = smem + ((t & 1) * 2 + mat) * 16384 + half * 8192;
    const u16* gsrc = mat ? W : A;
    const int gr0 = (mat ? bcol : brow) + half * 128;
#pragma unroll
    for (int l = 0; l < 2; ++l) {
      int e = l * 4096 + tid * 8;                  // elem in half-tile
      int r = e >> 6, cb = (e & 63) << 1;          // row, byte-col (16-aligned)
      int scol = (cb ^ ((r & 7) << 4)) >> 1;       // inverse-swizzled source col
      gload16(gsrc + (size_t)(gr0 + r) * 512 + t * 64 + scol, db + e);
    }
  };

  // prologue: tiles 0 and 1 (16 loads); vmcnt(8)+BAR => tile0 resident chip-wide
  stage(0, 0, 0); stage(0, 0, 1); stage(0, 1, 0); stage(0, 1, 1);
  stage(1, 0, 0); stage(1, 0, 1); stage(1, 1, 0); stage(1, 1, 1);
  VMW(8);
  BAR();

  bfrag b0_[4];                                    // loop-carried (B nh0 of tile t)
  {
    const char* B0_ = (const char*)(smem + 1 * 16384);
#pragma unroll
    for (int n = 0; n < 2; ++n) {
      int rb = rowB0 + n * 16;
#pragma unroll
      for (int ks = 0; ks < 2; ++ks)
        b0_[n * 2 + ks] = *(const bfrag*)(B0_ + rb * 128 + ((ks * 64 + g * 16) ^ ((rb & 7) << 4)));
    }
  }

  for (int t = 0; t < 8; ++t) {
    const char* As_ = (const char*)(smem + ((t & 1) * 2 + 0) * 16384);
    const char* Bs_ = (const char*)(smem + ((t & 1) * 2 + 1) * 16384);
    bfrag a_[8], b1_[4];

    // ---- P1: ds A(mh0) [8]; MFMA Q(0,0) uses b0_ carried from prev P4 ----
#pragma unroll
    for (int i = 0; i < 4; ++i) {
      int ra = rowA0 + i * 16;
#pragma unroll
      for (int ks = 0; ks < 2; ++ks)
        a_[i * 2 + ks] = *(const bfrag*)(As_ + ra * 128 + ((ks * 64 + g * 16) ^ ((ra & 7) << 4)));
    }
    BAR();
    __builtin_amdgcn_s_setprio(1);
    MFMAQ(0, 0, b0_);
    __builtin_amdgcn_s_setprio(0);
    BAR();

    // ---- P2: ds B(nh1) [4] ----
#pragma unroll
    for (int n = 0; n < 2; ++n) {
      int rb = rowB0 + 32 + n * 16;
#pragma unroll
      for (int ks = 0; ks < 2; ++ks)
        b1_[n * 2 + ks] = *(const bfrag*)(Bs_ + rb * 128 + ((ks * 64 + g * 16) ^ ((rb & 7) << 4)));
    }
    BAR();
    __builtin_amdgcn_s_setprio(1);
    MFMAQ(0, 1, b1_);
    __builtin_amdgcn_s_setprio(0);
    BAR();

    // ---- P3: ds A(mh1) [8]; stage t+2 B halves (B regions free after P2 bar) ----
#pragma unroll
    for (int i = 0; i < 4; ++i) {
      int ra = rowA0 + 64 + i * 16;
#pragma unroll
      for (int ks = 0; ks < 2; ++ks)
        a_[i * 2 + ks] = *(const bfrag*)(As_ + ra * 128 + ((ks * 64 + g * 16) ^ ((ra & 7) << 4)));
    }
    SCHED0();                                      // pin: reads issue before stages
    if (t + 2 < 8) { stage(t + 2, 1, 0); stage(t + 2, 1, 1); }
    BAR();
    __builtin_amdgcn_s_setprio(1);
    MFMAQ(1, 1, b1_);
    __builtin_amdgcn_s_setprio(0);
    BAR();

    // ---- P4: stage t+2 A halves; VMW then BAR (cross-wave t+1 drain);
    //          prefetch b0_ of t+1 from buf nxt [4] ----
    if (t + 2 < 8) { stage(t + 2, 0, 0); stage(t + 2, 0, 1); }
    if (t < 6) { VMW(8); } else if (t == 6) { VMW(0); }
    BAR();
    __builtin_amdgcn_s_setprio(1);
    MFMAQ(1, 0, b0_);
    __builtin_amdgcn_s_setprio(0);
    if (t < 7) {
      const char* Bn_ = (const char*)(smem + (((t + 1) & 1) * 2 + 1) * 16384);
#pragma unroll
      for (int n = 0; n < 2; ++n) {
        int rb = rowB0 + n * 16;
#pragma unroll
        for (int ks = 0; ks < 2; ++ks)
          b0_[n * 2 + ks] = *(const bfrag*)(Bn_ + rb * 128 + ((ks * 64 + g * 16) ^ ((rb & 7) << 4)));
      }
    }
    BAR();
  }

  // epilogue (R6): D frag mapping col = c15, row = g*4 + r
  {
    const float SCALE = 0.17677669529663687f;      // 32^-0.5
    const int win0 = (brow + wr * 128) >> 6;       // first window of this wave
#pragma unroll
    for (int n = 0; n < 4; ++n) {
      int c = bcol + wc * 64 + n * 16 + c15;       // 0..1535
      float bz = bias[c];
      int which = c >> 9;                          // block-uniform: 0=q 1=k 2=v
      int cq = c & 511, h = cq >> 5, d = cq & 31;
      size_t pb0 = ((size_t)(win0 * NHEAD + h)) << 11;   // (win,head) slab, 2048 elems
      size_t pb1 = pb0 + ((size_t)NHEAD << 11);          // win0+1
      if (which == 2) {
        u16* v0 = vws + pb0 + (d << 6);
        u16* v1 = vws + pb1 + (d << 6);
#pragma unroll
        for (int i = 0; i < 8; ++i) {
          u16* vp = (i < 4) ? v0 : v1;
#pragma unroll
          for (int r = 0; r < 4; ++r) {
            int tok = (i & 3) * 16 + g * 4 + r;
            vp[tok] = f2bf(acc[i][n][r] + bz);
          }
        }
      } else {
        const float s = (which == 0) ? SCALE : 1.0f;
        u16* base = (which == 0) ? qws : kws;
        u16* q0 = base + pb0 + d;
        u16* q1 = base + pb1 + d;
#pragma unroll
        for (int i = 0; i < 8; ++i) {
          u16* qp = (i < 4) ? q0 : q1;
#pragma unroll
          for (int r = 0; r < 4; ++r) {
            int tok = (i & 3) * 16 + g * 4 + r;
            qp[tok << 5] = f2bf((acc[i][n][r] + bz) * s);
          }
        }
      }
    }
  }
}

// ---------------------------------------------------------------------------
// fused attention + proj: 1 window/block, 512 threads (8 waves, 2 heads each).
// Per head: S^T = mfma(K,Q) + combB bias; softmax in-lane+2shfl; P -> wave-
// private swizzled LDS slot; PV via vT -> y frags -> y LDS [64][520] (padded).
// Then block-wide proj: out = y @ wp^T + proj_b (f32, direct store).
// LDS: y 66560 B + P 8*8192 B = 132096 B -> 1 block/CU.
// ---------------------------------------------------------------------------
__global__ __launch_bounds__(512, 1) void k_attn_proj(const u16* __restrict__ qws,
                                                      const u16* __restrict__ kws,
                                                      const u16* __restrict__ vws,
                                                      const u16* __restrict__ combB,
                                                      const u16* __restrict__ wp,
                                                      const float* __restrict__ proj_b,
                                                      float* __restrict__ out) {
  extern __shared__ __align__(16) u16 sm2[];
  u16* yl = sm2;                                   // [64][520] bf16
  const int tid = threadIdx.x, w = tid >> 6, lane = tid & 63;
  const int c15 = lane & 15, g = lane >> 4, g4 = g * 4;
  u16* pl = sm2 + 33280 + w * 4096;                // wave-private P slot [64][64]
  const int b = blockIdx.x;
  const ffrag zf = {0.f, 0.f, 0.f, 0.f};

  for (int hh = 0; hh < 2; ++hh) {
    const int h = w * 2 + hh;
    const int p = b * NHEAD + h;

    const u16* qb_ = qws + (size_t)p * (NTOK * HDIM);
    const u16* kb_ = kws + (size_t)p * (NTOK * HDIM);
    bfrag qa[4], ka[4];
#pragma unroll
    for (int t = 0; t < 4; ++t) {
      qa[t] = *reinterpret_cast<const bfrag*>(qb_ + (t * 16 + c15) * HDIM + g * 8);
      ka[t] = *reinterpret_cast<const bfrag*>(kb_ + (t * 16 + c15) * HDIM + g * 8);
    }
    const u16* cB = combB + ((size_t)(((b & (NW - 1)) << 4) + h) << 12);  // [row][col]

#pragma unroll
    for (int it = 0; it < 4; ++it) {
      int row = it * 16 + c15;           // score row
      float l[4][4];
      float mx = -3.0e38f;
#pragma unroll
      for (int jt = 0; jt < 4; ++jt) {
        ffrag s = mfma16(ka[jt], qa[it], zf);   // S^T tile: D[4g+r][c15]
        uint2 cw = *reinterpret_cast<const uint2*>(cB + row * 64 + jt * 16 + g4);
        l[jt][0] = s[0] + bfhi2f(cw.x << 16);
        l[jt][1] = s[1] + bfhi2f(cw.x & 0xffff0000u);
        l[jt][2] = s[2] + bfhi2f(cw.y << 16);
        l[jt][3] = s[3] + bfhi2f(cw.y & 0xffff0000u);
        mx = fmaxf(mx, fmaxf(fmaxf(l[jt][0], l[jt][1]), fmaxf(l[jt][2], l[jt][3])));
      }
      mx = fmaxf(mx, __shfl_xor(mx, 16));
      mx = fmaxf(mx, __shfl_xor(mx, 32));
      float sum = 0.f;
#pragma unroll
      for (int jt = 0; jt < 4; ++jt)
#pragma unroll
        for (int r = 0; r < 4; ++r) {
          float e = __expf(l[jt][r] - mx);
          l[jt][r] = e;
          sum += e;
        }
      sum += __shfl_xor(sum, 16);
      sum += __shfl_xor(sum, 32);
      float inv = 1.0f / sum;
#pragma unroll
      for (int jt = 0; jt < 4; ++jt) {
        union { u16 u[4]; uint2 v; } pk;
#pragma unroll
        for (int r = 0; r < 4; ++r) pk.u[r] = f2bf(l[jt][r] * inv);
        int off = row * 64 + ((jt * 16 + g4) ^ ((row & 7) << 3));
        *reinterpret_cast<uint2*>(&pl[off]) = pk.v;
      }
    }
    // P is wave-private: no block sync needed; compiler orders ds ops in-wave.

    const u16* vb_ = vws + (size_t)p * (HDIM * NTOK);
    ffrag o0[4] = {zf, zf, zf, zf}, o1[4] = {zf, zf, zf, zf};
#pragma unroll
    for (int ks = 0; ks < 2; ++ks) {
      bfrag vf0 = *reinterpret_cast<const bfrag*>(vb_ + c15 * NTOK + ks * 32 + g * 8);
      bfrag vf1 = *reinterpret_cast<const bfrag*>(vb_ + (16 + c15) * NTOK + ks * 32 + g * 8);
#pragma unroll
      for (int i = 0; i < 4; ++i) {
        int prow = i * 16 + c15;
        bfrag pa = *reinterpret_cast<const bfrag*>(
            &pl[prow * 64 + ((ks * 32 + g * 8) ^ ((prow & 7) << 3))]);
        o0[i] = mfma16(pa, vf0, o0[i]);
        o1[i] = mfma16(pa, vf1, o1[i]);
      }
    }
    // y frags -> LDS (cols h*32 .. h*32+31)
#pragma unroll
    for (int i = 0; i < 4; ++i)
#pragma unroll
      for (int r = 0; r < 4; ++r) {
        int tok = i * 16 + g4 + r;
        yl[tok * 520 + h * 32 + c15] = f2bf(o0[i][r]);
        yl[tok * 520 + h * 32 + 16 + c15] = f2bf(o1[i][r]);
      }
  }
  __syncthreads();

  // ---- proj: out[64][512] = y @ wp^T + proj_b; wave w owns cols w*64..+63 ----
  ffrag acc[4][4];
#pragma unroll
  for (int i = 0; i < 4; ++i)
#pragma unroll
    for (int n = 0; n < 4; ++n) acc[i][n] = zf;

  for (int ks = 0; ks < 16; ++ks) {
    bfrag a_[4], b_[4];
#pragma unroll
    for (int i = 0; i < 4; ++i)
      a_[i] = *reinterpret_cast<const bfrag*>(yl + (i * 16 + c15) * 520 + ks * 32 + g * 8);
#pragma unroll
    for (int n = 0; n < 4; ++n)
      b_[n] = *reinterpret_cast<const bfrag*>(wp + (size_t)(w * 64 + n * 16 + c15) * 512 + ks * 32 + g * 8);
#pragma unroll
    for (int i = 0; i < 4; ++i)
#pragma unroll
      for (int n = 0; n < 4; ++n)
        acc[i][n] = mfma16(a_[i], b_[n], acc[i][n]);
  }

#pragma unroll
  for (int n = 0; n < 4; ++n) {
    int c = w * 64 + n * 16 + c15;
    float bz = proj_b[c];
    float* po = out + (size_t)b * NTOK * CDIM + c;
#pragma unroll
    for (int i = 0; i < 4; ++i)
#pragma unroll
      for (int r = 0; r < 4; ++r)
        po[(size_t)(i * 16 + g4 + r) * CDIM] = acc[i][n][r] + bz;
  }
}

// ---------------------------------------------------------------------------
extern "C" void kernel_launch(void* const* d_in, const int* in_sizes, int n_in,
                              void* d_out, int out_size, void* d_ws, size_t ws_size,
                              hipStream_t stream) {
  const float* x      = (const float*)d_in[0];
  const float* mask   = (const float*)d_in[1];
  const float* qkv_w  = (const float*)d_in[2];
  const float* qkv_b  = (const float*)d_in[3];
  const float* proj_w = (const float*)d_in[4];
  const float* proj_b = (const float*)d_in[5];
  const float* rpb    = (const float*)d_in[6];
  const int*   rel    = (const int*)d_in[7];
  float* out = (float*)d_out;

  char* ws = (char*)d_ws;
  constexpr size_t SZ_QKV = (size_t)NWIN_TOT * NHEAD * NTOK * HDIM * 2;  // 64 MiB each
  u16* qws = (u16*)(ws);
  u16* kws = (u16*)(ws + SZ_QKV);
  u16* vws = (u16*)(ws + 2 * SZ_QKV);
  u16* xb  = (u16*)(ws + 3 * SZ_QKV);   // x as bf16
  u16* wq  = (u16*)(ws + 4 * SZ_QKV);
  u16* wp  = (u16*)(ws + 4 * SZ_QKV + 1572864);
  u16* combB = (u16*)(ws + 4 * SZ_QKV + 1572864 + 524288);  // 8 MiB

  hipFuncSetAttribute((const void*)k_gemm8,
                      hipFuncAttributeMaxDynamicSharedMemorySize, 131072);
  hipFuncSetAttribute((const void*)k_attn_proj,
                      hipFuncAttributeMaxDynamicSharedMemorySize, 132096);

  k_prep<<<dim3(36864), dim3(256), 0, stream>>>(x, qkv_w, proj_w, rel, rpb, mask,
                                                xb, wq, wp, combB);
  k_gemm8<<<dim3(256 * 6), dim3(512), 131072, stream>>>(xb, wq, qkv_b, qws, kws, vws);
  k_attn_proj<<<dim3(NWIN_TOT), dim3(512), 132096, stream>>>(qws, kws, vws, combB,
                                                             wp, proj_b, out);
}

// Round 9
// 324.467 us; speedup vs baseline: 1.0197x; 1.0197x over previous
//
#include <hip/hip_runtime.h>
#include <hip/hip_bf16.h>

typedef unsigned short u16;
typedef __attribute__((ext_vector_type(8))) short bfrag;   // 8 x bf16 (4 VGPRs)
typedef __attribute__((ext_vector_type(4))) float ffrag;   // 4 x f32

// ---- problem constants ----
#define NWIN_TOT 1024      // B_ = 16 * 64 windows
#define NTOK 64            // tokens per window
#define CDIM 512
#define NHEAD 16
#define HDIM 32
#define NW 64              // mask windows

__device__ __forceinline__ u16 f2bf(float f) {
  union { float f; unsigned u; } v; v.f = f;
  unsigned r = v.u + 0x7fffu + ((v.u >> 16) & 1u);
  return (u16)(r >> 16);
}

__device__ __forceinline__ float bfhi2f(unsigned hi_bits) {  // bf16 in high 16 bits
  union { unsigned u; float f; } v; v.u = hi_bits; return v.f;
}

__device__ __forceinline__ ffrag mfma16(bfrag a, bfrag b, ffrag c) {
  return __builtin_amdgcn_mfma_f32_16x16x32_bf16(a, b, c, 0, 0, 0);
}

// async global->LDS, 16B per lane, linear LDS dest (wave base + lane*16)
__device__ __forceinline__ void gload16(const u16* src, u16* lds) {
  __builtin_amdgcn_global_load_lds(
      (const __attribute__((address_space(1))) unsigned int*)src,
      (__attribute__((address_space(3))) unsigned int*)lds, 16, 0, 0);
}

#define BAR() __builtin_amdgcn_s_barrier()
#define VMW(n) do { asm volatile("s_waitcnt vmcnt(" #n ")" ::: "memory"); \
                    __builtin_amdgcn_sched_barrier(0); } while (0)

// ---------------------------------------------------------------------------
// prep: x -> bf16; weights -> bf16; combined bias+mask table (bf16, row-major)
// ---------------------------------------------------------------------------
__global__ __launch_bounds__(256) void k_prep(const float* __restrict__ x,
                                              const float* __restrict__ qkv_w,
                                              const float* __restrict__ proj_w,
                                              const int*   __restrict__ rel_index,
                                              const float* __restrict__ rpb,
                                              const float* __restrict__ mask,
                                              u16* __restrict__ xb,
                                              u16* __restrict__ wq, u16* __restrict__ wp,
                                              u16* __restrict__ combB) {
  int i = blockIdx.x * 256 + threadIdx.x;
  if (i < 4194304) {            // x -> bf16, 8 elems/thread
    int e = i * 8;
    const float4* xp = reinterpret_cast<const float4*>(x + e);
    float4 lo = xp[0], hi = xp[1];
    union { u16 u[8]; bfrag v; } pk;
    pk.u[0] = f2bf(lo.x); pk.u[1] = f2bf(lo.y); pk.u[2] = f2bf(lo.z); pk.u[3] = f2bf(lo.w);
    pk.u[4] = f2bf(hi.x); pk.u[5] = f2bf(hi.y); pk.u[6] = f2bf(hi.z); pk.u[7] = f2bf(hi.w);
    *reinterpret_cast<bfrag*>(xb + e) = pk.v;
    return;
  }
  i -= 4194304;
  if (i < 786432) { wq[i] = f2bf(qkv_w[i]); return; }
  i -= 786432;
  if (i < 262144) { wp[i] = f2bf(proj_w[i]); return; }
  i -= 262144;
  {                              // combB
    int wh = i >> 12, rc = i & 4095;
    int w0 = wh >> 4, h = wh & 15;
    combB[i] = f2bf(rpb[rel_index[rc] * 16 + h] + mask[(w0 << 12) + rc]);
  }
}

// ---------------------------------------------------------------------------
// 3-stage 256x128 GEMM, BK=64, 8 waves (4M x 2N), K=512 (8 K-tiles).
// LDS 144 KiB: 3 buffers x (A 256x64 + B 128x64) bf16.
//
// 3-buffer safety: stage(t+2) writes buf (t+2)%3 = buf (t-1)%3, whose last
// readers all passed tile t-1's trailing barrier before tile t began (max
// wave skew < 1 tile with >=1 barrier/tile). No region ledger needed.
// vmcnt ledger: 6 loads/tile (A=4, B=2). At end of tile t, outstanding =
// t+1's 6 (issued during t-1) + t+2's 6 (issued during t) -> VMW(6) drains
// t+1 exactly; trailing BAR makes it cross-wave. t==6 -> VMW(0). Prefetch
// distance >= 1 full tile (~4 phases) covers HBM latency.
// Phases: 2/tile (ks-half each: 8 ds_read_b128 + 16 MFMA per wave).
// ---------------------------------------------------------------------------
template<int EPI>
__global__ __launch_bounds__(512, 1) void k_gemm3(const u16* __restrict__ A,
                                                  const u16* __restrict__ W,
                                                  const float* __restrict__ bias,
                                                  u16* __restrict__ qws, u16* __restrict__ kws,
                                                  u16* __restrict__ vws,
                                                  float* __restrict__ out) {
  constexpr int NT = (EPI == 0) ? 12 : 4;          // N / 128
  constexpr int NWG = 256 * NT;                    // M/256=256 m-tiles
  extern __shared__ __align__(16) u16 smem[];      // 3 * 24576 u16

  // XCD-bijective swizzle (NWG % 8 == 0), N-inner tile order
  const int bid = blockIdx.x;
  const int tile = (bid & 7) * (NWG >> 3) + (bid >> 3);
  const int bn = tile % NT, bm = tile / NT;
  const int brow = bm << 8, bcol = bn << 7;

  const int tid = threadIdx.x;
  const int wv = tid >> 6, lane = tid & 63, c15 = lane & 15, g = lane >> 4;
  const int g4 = g * 4;
  const int wr = wv >> 1, wc = wv & 1;             // 4M x 2N wave grid
  const ffrag zf = {0.f, 0.f, 0.f, 0.f};

  ffrag acc[4][4];
#pragma unroll
  for (int i = 0; i < 4; ++i)
#pragma unroll
    for (int n = 0; n < 4; ++n) acc[i][n] = zf;

  // stage K-tile t (A: 4 loads/thread, B: 2 loads/thread); linear LDS dest,
  // inverse-swizzled global source (G21).
  auto stageA = [&](int t) {
    u16* db = smem + (t % 3) * 24576;
#pragma unroll
    for (int l = 0; l < 4; ++l) {
      int e = l * 4096 + tid * 8;
      int r = e >> 6, cb = (e & 63) << 1;
      int scol = (cb ^ ((r & 7) << 4)) >> 1;
      gload16(A + (size_t)(brow + r) * 512 + t * 64 + scol, db + e);
    }
  };
  auto stageB = [&](int t) {
    u16* db = smem + (t % 3) * 24576 + 16384;
#pragma unroll
    for (int l = 0; l < 2; ++l) {
      int e = l * 4096 + tid * 8;
      int r = e >> 6, cb = (e & 63) << 1;
      int scol = (cb ^ ((r & 7) << 4)) >> 1;
      gload16(W + (size_t)(bcol + r) * 512 + t * 64 + scol, db + e);
    }
  };

  // prologue: tiles 0,1 (12 loads); VMW(6) => tile0 resident; BAR cross-wave
  stageA(0); stageB(0); stageA(1); stageB(1);
  VMW(6);
  BAR();

  for (int t = 0; t < 8; ++t) {
    const char* As_ = (const char*)(smem + (t % 3) * 24576);
    const char* Bs_ = As_ + 32768;                 // B region (bytes)
    bfrag a_[4], b_[4];

    // ---- P1: ks=0 ----
#pragma unroll
    for (int i = 0; i < 4; ++i) {
      int ra = wr * 64 + i * 16 + c15;
      a_[i] = *(const bfrag*)(As_ + ra * 128 + ((g * 16) ^ ((ra & 7) << 4)));
    }
#pragma unroll
    for (int n = 0; n < 4; ++n) {
      int rb = wc * 64 + n * 16 + c15;
      b_[n] = *(const bfrag*)(Bs_ + rb * 128 + ((g * 16) ^ ((rb & 7) << 4)));
    }
    if (t + 2 < 8) stageA(t + 2);
    BAR();
    __builtin_amdgcn_s_setprio(1);
#pragma unroll
    for (int i = 0; i < 4; ++i)
#pragma unroll
      for (int n = 0; n < 4; ++n)
        acc[i][n] = mfma16(a_[i], b_[n], acc[i][n]);
    __builtin_amdgcn_s_setprio(0);

    // ---- P2: ks=1 ----
#pragma unroll
    for (int i = 0; i < 4; ++i) {
      int ra = wr * 64 + i * 16 + c15;
      a_[i] = *(const bfrag*)(As_ + ra * 128 + ((64 + g * 16) ^ ((ra & 7) << 4)));
    }
#pragma unroll
    for (int n = 0; n < 4; ++n) {
      int rb = wc * 64 + n * 16 + c15;
      b_[n] = *(const bfrag*)(Bs_ + rb * 128 + ((64 + g * 16) ^ ((rb & 7) << 4)));
    }
    if (t + 2 < 8) stageB(t + 2);
    __builtin_amdgcn_s_setprio(1);
#pragma unroll
    for (int i = 0; i < 4; ++i)
#pragma unroll
      for (int n = 0; n < 4; ++n)
        acc[i][n] = mfma16(a_[i], b_[n], acc[i][n]);
    __builtin_amdgcn_s_setprio(0);
    if (t < 6) { VMW(6); BAR(); }
    else if (t == 6) { VMW(0); BAR(); }
  }

  // ---- epilogue: D frag mapping col = c15, row = g4 + r ----
  if (EPI == 0) {
    const float SCALE = 0.17677669529663687f;      // 32^-0.5
    const int which = bn >> 2;                     // 0=q 1=k 2=v (block-uniform)
    const int win = (brow >> 6) + wr;              // wave rows = one window
#pragma unroll
    for (int n = 0; n < 4; ++n) {
      int c = bcol + wc * 64 + n * 16 + c15;       // 0..1535
      float bz = bias[c];
      int cq = c & 511, h = cq >> 5, d = cq & 31;
      size_t slab = ((size_t)(win * NHEAD + h)) << 11;
      if (which == 2) {
        u16* vp = vws + slab + (d << 6);
#pragma unroll
        for (int i = 0; i < 4; ++i) {
          int tok0 = i * 16 + g4;
          union { u16 u[4]; uint2 v; } pk;
#pragma unroll
          for (int r = 0; r < 4; ++r) pk.u[r] = f2bf(acc[i][n][r] + bz);
          *reinterpret_cast<uint2*>(vp + tok0) = pk.v;
        }
      } else {
        const float s = (which == 0) ? SCALE : 1.0f;
        u16* qp = ((which == 0) ? qws : kws) + slab + d;
#pragma unroll
        for (int i = 0; i < 4; ++i)
#pragma unroll
          for (int r = 0; r < 4; ++r)
            qp[(i * 16 + g4 + r) << 5] = f2bf((acc[i][n][r] + bz) * s);
      }
    }
  } else {
#pragma unroll
    for (int n = 0; n < 4; ++n) {
      int c = bcol + wc * 64 + n * 16 + c15;
      float bz = bias[c];
      float* po = out + (size_t)(brow + wr * 64) * CDIM + c;
#pragma unroll
      for (int i = 0; i < 4; ++i)
#pragma unroll
        for (int r = 0; r < 4; ++r)
          po[(size_t)(i * 16 + g4 + r) * CDIM] = acc[i][n][r] + bz;
    }
  }
}

// ---------------------------------------------------------------------------
// attention (R6): 1 wave per (window, head). S^T = mfma(K,Q); softmax in-lane
// +2shfl; combB bias; P -> swizzled LDS -> A-frags; PV via vT; y restaged
// through LDS [64][136] for coalesced 256B-row stores.
// ---------------------------------------------------------------------------
__global__ __launch_bounds__(256) void k_attn(const u16* __restrict__ qws,
                                              const u16* __restrict__ kws,
                                              const u16* __restrict__ vws,
                                              const u16* __restrict__ combB,
                                              u16* __restrict__ yws) {
  __shared__ __align__(16) u16 plds[4][NTOK * NTOK];  // 8 KiB per wave; reused for y
  const int tid = threadIdx.x, w = tid >> 6, lane = tid & 63;
  const int c15 = lane & 15, g = lane >> 4, g4 = g * 4;
  const int p = blockIdx.x * 4 + w;
  const int b = p >> 4, h = p & 15;

  const u16* qb_ = qws + (size_t)p * (NTOK * HDIM);
  const u16* kb_ = kws + (size_t)p * (NTOK * HDIM);
  bfrag qa[4], ka[4];
#pragma unroll
  for (int t = 0; t < 4; ++t) {
    qa[t] = *reinterpret_cast<const bfrag*>(qb_ + (t * 16 + c15) * HDIM + g * 8);
    ka[t] = *reinterpret_cast<const bfrag*>(kb_ + (t * 16 + c15) * HDIM + g * 8);
  }

  const u16* cB = combB + ((size_t)(((b & (NW - 1)) << 4) + h) << 12);  // [row][col]
  u16* pl = plds[w];
  const ffrag zf = {0.f, 0.f, 0.f, 0.f};

#pragma unroll
  for (int it = 0; it < 4; ++it) {
    int row = it * 16 + c15;           // score row
    float l[4][4];
    float mx = -3.0e38f;
#pragma unroll
    for (int jt = 0; jt < 4; ++jt) {
      ffrag s = mfma16(ka[jt], qa[it], zf);   // S^T tile: D[4g+r][c15]
      uint2 cw = *reinterpret_cast<const uint2*>(cB + row * 64 + jt * 16 + g4);
      l[jt][0] = s[0] + bfhi2f(cw.x << 16);
      l[jt][1] = s[1] + bfhi2f(cw.x & 0xffff0000u);
      l[jt][2] = s[2] + bfhi2f(cw.y << 16);
      l[jt][3] = s[3] + bfhi2f(cw.y & 0xffff0000u);
      mx = fmaxf(mx, fmaxf(fmaxf(l[jt][0], l[jt][1]), fmaxf(l[jt][2], l[jt][3])));
    }
    mx = fmaxf(mx, __shfl_xor(mx, 16));
    mx = fmaxf(mx, __shfl_xor(mx, 32));
    float sum = 0.f;
#pragma unroll
    for (int jt = 0; jt < 4; ++jt)
#pragma unroll
      for (int r = 0; r < 4; ++r) {
        float e = __expf(l[jt][r] - mx);
        l[jt][r] = e;
        sum += e;
      }
    sum += __shfl_xor(sum, 16);
    sum += __shfl_xor(sum, 32);
    float inv = 1.0f / sum;
#pragma unroll
    for (int jt = 0; jt < 4; ++jt) {
      union { u16 u[4]; uint2 v; } pk;
#pragma unroll
      for (int r = 0; r < 4; ++r) pk.u[r] = f2bf(l[jt][r] * inv);
      int off = row * 64 + ((jt * 16 + g4) ^ ((row & 7) << 3));
      *reinterpret_cast<uint2*>(&pl[off]) = pk.v;
    }
  }
  __syncthreads();

  const u16* vb_ = vws + (size_t)p * (HDIM * NTOK);
  ffrag o0[4] = {zf, zf, zf, zf}, o1[4] = {zf, zf, zf, zf};
#pragma unroll
  for (int ks = 0; ks < 2; ++ks) {
    bfrag vf0 = *reinterpret_cast<const bfrag*>(vb_ + c15 * NTOK + ks * 32 + g * 8);
    bfrag vf1 = *reinterpret_cast<const bfrag*>(vb_ + (16 + c15) * NTOK + ks * 32 + g * 8);
#pragma unroll
    for (int i = 0; i < 4; ++i) {
      int prow = i * 16 + c15;
      bfrag pa = *reinterpret_cast<const bfrag*>(
          &pl[prow * 64 + ((ks * 32 + g * 8) ^ ((prow & 7) << 3))]);
      o0[i] = mfma16(pa, vf0, o0[i]);
      o1[i] = mfma16(pa, vf1, o1[i]);
    }
  }
  __syncthreads();                                 // all waves done reading P

  // y -> LDS [64][136] (padded), then block-cooperative coalesced store
  u16* yl = &plds[0][0];
#pragma unroll
  for (int i = 0; i < 4; ++i)
#pragma unroll
    for (int r = 0; r < 4; ++r) {
      int tok = i * 16 + g4 + r;
      yl[tok * 136 + w * 32 + c15] = f2bf(o0[i][r]);
      yl[tok * 136 + w * 32 + 16 + c15] = f2bf(o1[i][r]);
    }
  __syncthreads();
  {
    const int b2 = blockIdx.x >> 2;
    const int h0 = (blockIdx.x * 4) & 15;          // first head of block
    int row = tid >> 2, seg = tid & 3;             // 64 rows x 4 segs of 32 elems
    const u16* src = yl + row * 136 + seg * 32;
    u16* dst = yws + ((size_t)b2 * NTOK + row) * CDIM + h0 * HDIM + seg * 32;
    bfrag v0 = *(const bfrag*)(src);
    bfrag v1 = *(const bfrag*)(src + 8);
    bfrag v2 = *(const bfrag*)(src + 16);
    bfrag v3 = *(const bfrag*)(src + 24);
    *(bfrag*)(dst) = v0;
    *(bfrag*)(dst + 8) = v1;
    *(bfrag*)(dst + 16) = v2;
    *(bfrag*)(dst + 24) = v3;
  }
}

// ---------------------------------------------------------------------------
extern "C" void kernel_launch(void* const* d_in, const int* in_sizes, int n_in,
                              void* d_out, int out_size, void* d_ws, size_t ws_size,
                              hipStream_t stream) {
  const float* x      = (const float*)d_in[0];
  const float* mask   = (const float*)d_in[1];
  const float* qkv_w  = (const float*)d_in[2];
  const float* qkv_b  = (const float*)d_in[3];
  const float* proj_w = (const float*)d_in[4];
  const float* proj_b = (const float*)d_in[5];
  const float* rpb    = (const float*)d_in[6];
  const int*   rel    = (const int*)d_in[7];
  float* out = (float*)d_out;

  char* ws = (char*)d_ws;
  constexpr size_t SZ_QKV = (size_t)NWIN_TOT * NHEAD * NTOK * HDIM * 2;  // 64 MiB each
  u16* qws = (u16*)(ws);
  u16* kws = (u16*)(ws + SZ_QKV);
  u16* vws = (u16*)(ws + 2 * SZ_QKV);
  u16* xb  = (u16*)(ws + 3 * SZ_QKV);   // x as bf16; dead after k_gemm3<0> ...
  u16* yws = xb;                        // ... so yws aliases it (written in k_attn)
  u16* wq  = (u16*)(ws + 4 * SZ_QKV);
  u16* wp  = (u16*)(ws + 4 * SZ_QKV + 1572864);
  u16* combB = (u16*)(ws + 4 * SZ_QKV + 1572864 + 524288);  // 8 MiB

  hipFuncSetAttribute((const void*)k_gemm3<0>,
                      hipFuncAttributeMaxDynamicSharedMemorySize, 147456);
  hipFuncSetAttribute((const void*)k_gemm3<1>,
                      hipFuncAttributeMaxDynamicSharedMemorySize, 147456);

  k_prep<<<dim3(36864), dim3(256), 0, stream>>>(x, qkv_w, proj_w, rel, rpb, mask,
                                                xb, wq, wp, combB);
  k_gemm3<0><<<dim3(256 * 12), dim3(512), 147456, stream>>>(xb, wq, qkv_b,
                                                            qws, kws, vws, nullptr);
  k_attn<<<dim3(NWIN_TOT * NHEAD / 4), dim3(256), 0, stream>>>(qws, kws, vws, combB, yws);
  k_gemm3<1><<<dim3(256 * 4), dim3(512), 147456, stream>>>(yws, wp, proj_b,
                                                           nullptr, nullptr, nullptr, out);
}